// Round 14
// baseline (240.736 us; speedup 1.0000x reference)
//
#include <hip/hip_runtime.h>
#include <math.h>

#define D_MODEL 1024
#define D_INNER 2048
#define DT_RANK 64
#define D_STATE 16
#define NBC 96   // DT_RANK + 2*D_STATE
#define BATCH 2
#define SEQ 1024
#define TOK (BATCH*SEQ)  // 2048
#define CS 32            // scan chunk size
#define NCH 32           // chunks per sequence
#define XKSPLIT 16       // x_proj K-split

typedef __attribute__((ext_vector_type(8))) short short8;
typedef __attribute__((ext_vector_type(4))) float f32x4;
typedef __attribute__((ext_vector_type(4))) unsigned short us4;

// ---------------- device helpers ----------------
__device__ __forceinline__ float softplus_f(float x) {
    return (x > 20.0f) ? x : log1pf(__expf(x));
}
__device__ __forceinline__ float gelu_f(float x) {
    return 0.5f * x * (1.0f + erff(x * 0.70710678118654752f));
}
__device__ __forceinline__ float silu_f(float x) {
    return x / (1.0f + __expf(-x));
}
__device__ __forceinline__ ushort f2bf(float f) {   // fp32 -> bf16 RNE
    unsigned u = __float_as_uint(f);
    unsigned r = (u + 0x7fffu + ((u >> 16) & 1u)) >> 16;
    return (ushort)r;
}
__device__ __forceinline__ float bf2f(ushort u) {
    return __uint_as_float(((unsigned)u) << 16);
}

// ---------------- prep: LN1 (blocks 0..TOK-1) + weight converts (rest) ----------------
__global__ void prep_kernel(const float* __restrict__ x, const float* __restrict__ g,
                            const float* __restrict__ b, ushort* __restrict__ ln_out,
                            const float* __restrict__ Wp, const float* __restrict__ Wo,
                            const float* __restrict__ W1, const float* __restrict__ W2,
                            const float* __restrict__ Wx, const float* __restrict__ Wdt,
                            ushort* __restrict__ Wpb, ushort* __restrict__ Wob,
                            ushort* __restrict__ W1b, ushort* __restrict__ W2b,
                            ushort* __restrict__ Wxb, ushort* __restrict__ Wdtb) {
    int tid = threadIdx.x;
    if (blockIdx.x < TOK) {
        int row = blockIdx.x;
        const float* xr = x + (size_t)row * D_MODEL;
        ushort* outr = ln_out + (size_t)row * D_MODEL;
        float4 v = ((const float4*)xr)[tid];
        float s  = v.x + v.y + v.z + v.w;
        float sq = v.x*v.x + v.y*v.y + v.z*v.z + v.w*v.w;
        #pragma unroll
        for (int o = 32; o > 0; o >>= 1) {
            s  += __shfl_down(s,  o);
            sq += __shfl_down(sq, o);
        }
        __shared__ float ss[4], ssq[4];
        int wid = tid >> 6, lane = tid & 63;
        if (lane == 0) { ss[wid] = s; ssq[wid] = sq; }
        __syncthreads();
        if (tid == 0) {
            float a = 0.f, c = 0.f;
            for (int i = 0; i < 4; i++) { a += ss[i]; c += ssq[i]; }
            ss[0] = a; ssq[0] = c;
        }
        __syncthreads();
        float mean = ss[0] * (1.0f / D_MODEL);
        float var  = ssq[0] * (1.0f / D_MODEL) - mean * mean;
        float rstd = rsqrtf(var + 1e-5f);
        float4 gg = ((const float4*)g)[tid];
        float4 bb = ((const float4*)b)[tid];
        ushort4 o;
        o.x = f2bf((v.x - mean) * rstd * gg.x + bb.x);
        o.y = f2bf((v.y - mean) * rstd * gg.y + bb.y);
        o.z = f2bf((v.z - mean) * rstd * gg.z + bb.z);
        o.w = f2bf((v.w - mean) * rstd * gg.w + bb.w);
        ((ushort4*)outr)[tid] = o;
        return;
    }
    int i = (blockIdx.x - TOK) * 256 + tid;  // float4 index
    const float* src; ushort* dst; int off;
    if      (i < 1048576) { src = Wp;  dst = Wpb;  off = i; }
    else if (i < 1572864) { src = Wo;  dst = Wob;  off = i - 1048576; }
    else if (i < 2097152) { src = W1;  dst = W1b;  off = i - 1572864; }
    else if (i < 2621440) { src = W2;  dst = W2b;  off = i - 2097152; }
    else if (i < 2670592) { src = Wx;  dst = Wxb;  off = i - 2621440; }
    else if (i < 2703360) { src = Wdt; dst = Wdtb; off = i - 2670592; }
    else return;
    float4 v = ((const float4*)src)[off];
    ushort4 o;
    o.x = f2bf(v.x); o.y = f2bf(v.y); o.z = f2bf(v.z); o.w = f2bf(v.w);
    ((ushort4*)dst)[off] = o;
}

// ---------------- LayerNorm -> bf16 out (LN2) ----------------
__global__ void ln_bf16_kernel(const float* __restrict__ x, const float* __restrict__ g,
                               const float* __restrict__ b, ushort* __restrict__ out) {
    int row = blockIdx.x;
    const float* xr = x + (size_t)row * D_MODEL;
    ushort* outr = out + (size_t)row * D_MODEL;
    int tid = threadIdx.x;
    float4 v = ((const float4*)xr)[tid];
    float s  = v.x + v.y + v.z + v.w;
    float sq = v.x*v.x + v.y*v.y + v.z*v.z + v.w*v.w;
    #pragma unroll
    for (int o = 32; o > 0; o >>= 1) {
        s  += __shfl_down(s,  o);
        sq += __shfl_down(sq, o);
    }
    __shared__ float ss[4], ssq[4];
    int wid = tid >> 6, lane = tid & 63;
    if (lane == 0) { ss[wid] = s; ssq[wid] = sq; }
    __syncthreads();
    if (tid == 0) {
        float a = 0.f, c = 0.f;
        for (int i = 0; i < 4; i++) { a += ss[i]; c += ssq[i]; }
        ss[0] = a; ssq[0] = c;
    }
    __syncthreads();
    float mean = ss[0] * (1.0f / D_MODEL);
    float var  = ssq[0] * (1.0f / D_MODEL) - mean * mean;
    float rstd = rsqrtf(var + 1e-5f);
    float4 gg = ((const float4*)g)[tid];
    float4 bb = ((const float4*)b)[tid];
    ushort4 o;
    o.x = f2bf((v.x - mean) * rstd * gg.x + bb.x);
    o.y = f2bf((v.y - mean) * rstd * gg.y + bb.y);
    o.z = f2bf((v.z - mean) * rstd * gg.z + bb.z);
    o.w = f2bf((v.w - mean) * rstd * gg.w + bb.w);
    ((ushort4*)outr)[tid] = o;
}

// ---------------- bf16 MFMA GEMM, 2-phase prefetch double-buffer ----------------
// C = act(A @ W^T [+bias]) [+res]; ACT: 0=none, 1=softplus, 2=gelu
template<int BM, int BN, int ACT, bool BIAS, bool RES, bool OUTBF>
__global__ __launch_bounds__(256)
void mfma_gemm(const ushort* __restrict__ A, const ushort* __restrict__ W,
               const float* __restrict__ bias,
               const float* __restrict__ res, int ldr,
               void* __restrict__ Cout, int ldc, int K) {
    constexpr int WM = BM / 2, WN = BN / 2, FM = WM / 16, FN = WN / 16;
    __shared__ __align__(16) ushort As[2][BM * 32];
    __shared__ __align__(16) ushort Ws[2][BN * 32];
    const int tid  = threadIdx.x;
    const int lane = tid & 63, w = tid >> 6;
    const int wr = w >> 1, wc = w & 1;
    const int row0 = blockIdx.y * BM, col0 = blockIdx.x * BN;
    const int l16 = lane >> 4, l15 = lane & 15;
    const int srow = tid >> 2;
    const int scol = (tid & 3) * 8;
    const int nk = K / 32;

    f32x4 acc[FM][FN] = {};

    auto stage = [&](int kk, int buf) {
        const int k0 = kk * 32;
        #pragma unroll
        for (int s = 0; s < BM / 64; s++) {
            const ushort* g = A + (size_t)(row0 + s * 64 + srow) * K + k0 + scol;
            __builtin_amdgcn_global_load_lds(
                (const __attribute__((address_space(1))) void*)g,
                (__attribute__((address_space(3))) void*)((char*)&As[buf][0] + s * 4096 + w * 1024),
                16, 0, 0);
        }
        #pragma unroll
        for (int s = 0; s < BN / 64; s++) {
            const ushort* g = W + (size_t)(col0 + s * 64 + srow) * K + k0 + scol;
            __builtin_amdgcn_global_load_lds(
                (const __attribute__((address_space(1))) void*)g,
                (__attribute__((address_space(3))) void*)((char*)&Ws[buf][0] + s * 4096 + w * 1024),
                16, 0, 0);
        }
    };

    stage(0, 0);
    __syncthreads();

    for (int kk = 0; kk < nk; kk++) {
        const int cur = kk & 1;
        if (kk + 1 < nk) stage(kk + 1, cur ^ 1);

        short8 a[FM], b[FN];
        #pragma unroll
        for (int m = 0; m < FM; m++)
            a[m] = *(const short8*)(&As[cur][0] + (wr * WM + m * 16 + l15) * 32 + l16 * 8);
        #pragma unroll
        for (int n = 0; n < FN; n++)
            b[n] = *(const short8*)(&Ws[cur][0] + (wc * WN + n * 16 + l15) * 32 + l16 * 8);
        #pragma unroll
        for (int m = 0; m < FM; m++)
            #pragma unroll
            for (int n = 0; n < FN; n++)
                acc[m][n] = __builtin_amdgcn_mfma_f32_16x16x32_bf16(a[m], b[n], acc[m][n], 0, 0, 0);
        __syncthreads();
    }

    #pragma unroll
    for (int m = 0; m < FM; m++) {
        const int r0 = row0 + wr * WM + m * 16 + l16 * 4;
        #pragma unroll
        for (int n = 0; n < FN; n++) {
            const int c = col0 + wc * WN + n * 16 + l15;
            const float bv = BIAS ? bias[c] : 0.f;
            #pragma unroll
            for (int q = 0; q < 4; q++) {
                const int r = r0 + q;
                float v = acc[m][n][q] + bv;
                if (ACT == 1) v = softplus_f(v);
                else if (ACT == 2) v = gelu_f(v);
                if (RES) v += res[(size_t)r * ldr + c];
                if (OUTBF) ((ushort*)Cout)[(size_t)r * ldc + c] = f2bf(v);
                else       ((float*)Cout)[(size_t)r * ldc + c] = v;
            }
        }
    }
}

// ---------------- x_proj split-K MFMA (2-phase prefetch) ----------------
__global__ __launch_bounds__(256)
void xproj_split_kernel(const ushort* __restrict__ A,   // [2048][2048] bf16
                        const ushort* __restrict__ W,   // [96][2048] bf16
                        float* __restrict__ part) {     // [XKSPLIT][2048][96]
    __shared__ __align__(16) ushort As[2][128 * 64];
    __shared__ __align__(16) ushort Bs[2][96 * 64];
    const int tid = threadIdx.x;
    const int lane = tid & 63, w = tid >> 6;
    const int l16 = lane >> 4, l15 = lane & 15;
    const int kbase = blockIdx.x * (D_INNER / XKSPLIT);   // *128
    const int row0 = blockIdx.y * 128;
    const int srow = tid >> 3;        // 0..31
    const int scol = (tid & 7) * 8;   // 0..56

    f32x4 acc[2][6] = {};

    auto stage = [&](int k0, int buf) {
        #pragma unroll
        for (int s = 0; s < 4; s++) {
            const ushort* g = A + (size_t)(row0 + s * 32 + srow) * D_INNER + kbase + k0 + scol;
            __builtin_amdgcn_global_load_lds(
                (const __attribute__((address_space(1))) void*)g,
                (__attribute__((address_space(3))) void*)((char*)&As[buf][0] + s * 4096 + w * 1024),
                16, 0, 0);
        }
        #pragma unroll
        for (int s = 0; s < 3; s++) {
            const ushort* g = W + (size_t)(s * 32 + srow) * D_INNER + kbase + k0 + scol;
            __builtin_amdgcn_global_load_lds(
                (const __attribute__((address_space(1))) void*)g,
                (__attribute__((address_space(3))) void*)((char*)&Bs[buf][0] + s * 4096 + w * 1024),
                16, 0, 0);
        }
    };

    stage(0, 0);
    __syncthreads();

    const int nk = (D_INNER / XKSPLIT) / 64;   // 2
    for (int kk = 0; kk < nk; kk++) {
        const int cur = kk & 1;
        if (kk + 1 < nk) stage((kk + 1) * 64, cur ^ 1);
        #pragma unroll
        for (int ks = 0; ks < 2; ks++) {
            short8 a[2], b[6];
            #pragma unroll
            for (int m = 0; m < 2; m++)
                a[m] = *(const short8*)(&As[cur][0] + (w * 32 + m * 16 + l15) * 64 + ks * 32 + l16 * 8);
            #pragma unroll
            for (int n = 0; n < 6; n++)
                b[n] = *(const short8*)(&Bs[cur][0] + (n * 16 + l15) * 64 + ks * 32 + l16 * 8);
            #pragma unroll
            for (int m = 0; m < 2; m++)
                #pragma unroll
                for (int n = 0; n < 6; n++)
                    acc[m][n] = __builtin_amdgcn_mfma_f32_16x16x32_bf16(a[m], b[n], acc[m][n], 0, 0, 0);
        }
        __syncthreads();
    }

    float* p = part + (size_t)blockIdx.x * D_INNER * NBC;
    #pragma unroll
    for (int m = 0; m < 2; m++) {
        const int r0 = row0 + w * 32 + m * 16 + l16 * 4;
        #pragma unroll
        for (int n = 0; n < 6; n++) {
            const int c = n * 16 + l15;
            #pragma unroll
            for (int q = 0; q < 4; q++)
                p[(size_t)(r0 + q) * NBC + c] = acc[m][n][q];
        }
    }
}

// reduce 16 K-slices -> dbc fp32 [row][96]; emit bf16 of dt columns (c<64)
__global__ void xproj_reduce_kernel(const float* __restrict__ part,
                                    float* __restrict__ dbc, ushort* __restrict__ dtin_b) {
    int i = blockIdx.x * 256 + threadIdx.x;   // 2048*96
    if (i >= D_INNER * NBC) return;
    float s = 0.f;
    #pragma unroll
    for (int k = 0; k < XKSPLIT; k++) s += part[(size_t)k * D_INNER * NBC + i];
    dbc[i] = s;
    int r = i / NBC, c = i - r * NBC;
    if (c < DT_RANK) dtin_b[r * DT_RANK + c] = f2bf(s);
}

// ---------------- causal depthwise conv (k=4) + silu; bf16 in, bf16 out ----------------
__global__ void conv_silu_kernel(const ushort* __restrict__ xzb, const float* __restrict__ cw,
                                 const float* __restrict__ cb, ushort* __restrict__ xcb) {
    int idx = blockIdx.x * 256 + threadIdx.x;      // TOK*D_INNER
    int c  = idx & (D_INNER - 1);
    int bt = idx >> 11;
    int b  = bt >> 10;
    int t  = bt & (SEQ - 1);
    float acc = cb[c];
    #pragma unroll
    for (int j = 0; j < 4; j++) {
        int tt = t - 3 + j;
        if (tt >= 0) acc += cw[c*4 + j] * bf2f(xzb[((size_t)(b*SEQ + tt)) * 4096 + c]);
    }
    xcb[idx] = f2bf(silu_f(acc));
}

// ---------------- chunked selective scan: LDS-staged; summaries in [b][c][d][n] ----------------
// block decode: cc FAST (bid&31) so consecutive blocks span all chunk indices
// (load balance: scan_final's prefix cost is proportional to cc).
__global__ __launch_bounds__(256, 8)
void scan_chunk_kernel(const ushort* __restrict__ dtb, const float* __restrict__ dbc,
                       const ushort* __restrict__ xcb, const float* __restrict__ A_log,
                       float* __restrict__ chunkA, float* __restrict__ chunkH) {
    __shared__ ushort dtS[64][36];
    __shared__ ushort xS[64][36];
    __shared__ float  BS[16][36];
    const int bid = blockIdx.x;
    const int cc = bid & 31, dg = (bid >> 5) & 31, b = bid >> 10;
    const int d0 = dg * 64;
    const int tid = threadIdx.x, lane = tid & 63, wv = tid >> 6;
    const int rbase = b * SEQ + cc * CS;

    #pragma unroll
    for (int k = 0; k < 8; k++) {
        int tt = k * 4 + wv;
        size_t row = (size_t)(rbase + tt);
        dtS[lane][tt] = dtb[row * D_INNER + d0 + lane];
        xS[lane][tt]  = xcb[row * D_INNER + d0 + lane];
    }
    #pragma unroll
    for (int k = 0; k < 2; k++) {
        int ii = k * 256 + tid;          // 0..511
        int val = ii & 15, tt = ii >> 4;
        BS[val][tt] = dbc[(size_t)(rbase + tt) * NBC + DT_RANK + val];
    }
    __syncthreads();

    const int d_local = tid >> 2, ng = tid & 3, nb = ng * 4;
    const int d = d0 + d_local;
    float Arow[4];
    #pragma unroll
    for (int j = 0; j < 4; j++) Arow[j] = -__expf(A_log[d * D_STATE + nb + j]);
    float h[4] = {};
    float cumdt = 0.f;
    #pragma unroll
    for (int it = 0; it < 8; ++it) {
        us4 dtu = *(const us4*)&dtS[d_local][it * 4];
        us4 xu  = *(const us4*)&xS[d_local][it * 4];
        f32x4 Bv[4];
        #pragma unroll
        for (int j = 0; j < 4; j++) Bv[j] = *(const f32x4*)&BS[nb + j][it * 4];
        #pragma unroll
        for (int q = 0; q < 4; ++q) {
            float dtv = bf2f(dtu[q]);
            float dtx = dtv * bf2f(xu[q]);
            cumdt += dtv;
            #pragma unroll
            for (int j = 0; j < 4; j++) {
                float dA = __expf(dtv * Arow[j]);
                h[j] = dA * h[j] + dtx * Bv[j][q];
            }
        }
    }
    // summary layout: ((b*NCH+c)*D_INNER + d)*D_STATE + n  -> f32x4 store
    size_t obase = ((size_t)((b * NCH + cc) * D_INNER) + d) * D_STATE + nb;
    f32x4 av, hv;
    #pragma unroll
    for (int j = 0; j < 4; j++) { av[j] = __expf(Arow[j] * cumdt); hv[j] = h[j]; }
    *(f32x4*)&chunkA[obase] = av;
    *(f32x4*)&chunkH[obase] = hv;
}

// pass2: in-register prefix over preceding chunks, seeded scan + fused gate -> yb bf16
// zS doubles as the y-staging tile (same-thread read-then-write).
__global__ __launch_bounds__(256, 8)
void scan_final_kernel(const ushort* __restrict__ dtb, const float* __restrict__ dbc,
                       const ushort* __restrict__ xcb, const float* __restrict__ A_log,
                       const float* __restrict__ chunkA, const float* __restrict__ chunkH,
                       const ushort* __restrict__ xzb,
                       const float* __restrict__ Dp, ushort* __restrict__ yb) {
    __shared__ ushort dtS[64][36];
    __shared__ ushort xS[64][36];
    __shared__ ushort zS[64][36];      // pass2: aliased as y-stage
    __shared__ float  BS[16][36];
    __shared__ float  CSld[16][36];
    const int bid = blockIdx.x;
    const int cc = bid & 31, dg = (bid >> 5) & 31, b = bid >> 10;
    const int d0 = dg * 64;
    const int tid = threadIdx.x, lane = tid & 63, wv = tid >> 6;
    const int rbase = b * SEQ + cc * CS;

    #pragma unroll
    for (int k = 0; k < 8; k++) {
        int tt = k * 4 + wv;
        size_t row = (size_t)(rbase + tt);
        dtS[lane][tt] = dtb[row * D_INNER + d0 + lane];
        xS[lane][tt]  = xcb[row * D_INNER + d0 + lane];
        zS[lane][tt]  = xzb[row * 4096 + 2048 + d0 + lane];
    }
    #pragma unroll
    for (int k = 0; k < 4; k++) {
        int ii = k * 256 + tid;          // 0..1023
        int val = ii & 31, tt = ii >> 5;
        float v = dbc[(size_t)(rbase + tt) * NBC + DT_RANK + val];
        if (val < 16) BS[val][tt] = v;
        else          CSld[val - 16][tt] = v;
    }

    const int d_local = tid >> 2, ng = tid & 3, nb = ng * 4;
    const int d = d0 + d_local;

    // in-register prefix over chunk summaries: hIn for this chunk
    f32x4 hv = {0.f, 0.f, 0.f, 0.f};
    #pragma unroll 4
    for (int c = 0; c < cc; ++c) {
        size_t off = ((size_t)((b * NCH + c) * D_INNER) + d) * D_STATE + nb;
        f32x4 a  = *(const f32x4*)&chunkA[off];
        f32x4 hl = *(const f32x4*)&chunkH[off];
        hv = a * hv + hl;
    }
    float Arow[4];
    #pragma unroll
    for (int j = 0; j < 4; j++) Arow[j] = -__expf(A_log[d * D_STATE + nb + j]);
    float h[4];
    #pragma unroll
    for (int j = 0; j < 4; j++) h[j] = hv[j];
    const float Dpv = Dp[d];
    __syncthreads();

    #pragma unroll
    for (int it = 0; it < 8; ++it) {
        us4 dtu = *(const us4*)&dtS[d_local][it * 4];
        us4 xu  = *(const us4*)&xS[d_local][it * 4];
        f32x4 Bv[4], Cv[4];
        #pragma unroll
        for (int j = 0; j < 4; j++) {
            Bv[j] = *(const f32x4*)&BS[nb + j][it * 4];
            Cv[j] = *(const f32x4*)&CSld[nb + j][it * 4];
        }
        float yv4[4];
        #pragma unroll
        for (int q = 0; q < 4; ++q) {
            float dtv = bf2f(dtu[q]);
            float dtx = dtv * bf2f(xu[q]);
            float yv = 0.f;
            #pragma unroll
            for (int j = 0; j < 4; j++) {
                float dA = __expf(dtv * Arow[j]);
                h[j] = dA * h[j] + dtx * Bv[j][q];
                yv += h[j] * Cv[j][q];
            }
            yv4[q] = yv;
        }
        #pragma unroll
        for (int q = 0; q < 4; ++q) {
            yv4[q] += __shfl_xor(yv4[q], 1);
            yv4[q] += __shfl_xor(yv4[q], 2);
        }
        if (ng == 0) {
            us4 zu = *(const us4*)&zS[d_local][it * 4];
            us4 xo = *(const us4*)&xS[d_local][it * 4];
            us4 o;
            #pragma unroll
            for (int q = 0; q < 4; ++q) {
                float z = bf2f(zu[q]);
                o[q] = f2bf((yv4[q] + bf2f(xo[q]) * Dpv) * silu_f(z));
            }
            *(us4*)&zS[d_local][it * 4] = o;   // overwrite own z slot with y
        }
    }
    __syncthreads();
    #pragma unroll
    for (int k = 0; k < 8; k++) {
        int tt = k * 4 + wv;
        yb[(size_t)(rbase + tt) * D_INNER + d0 + lane] = zS[lane][tt];
    }
}

// ---------------- launch ----------------
extern "C" void kernel_launch(void* const* d_in, const int* in_sizes, int n_in,
                              void* d_out, int out_size, void* d_ws, size_t ws_size,
                              hipStream_t stream) {
    const float* x    = (const float*)d_in[0];
    const float* n1g  = (const float*)d_in[1];
    const float* n1b  = (const float*)d_in[2];
    const float* Wp   = (const float*)d_in[3];
    const float* cw   = (const float*)d_in[4];
    const float* cb   = (const float*)d_in[5];
    const float* Wx   = (const float*)d_in[6];
    const float* Wdt  = (const float*)d_in[7];
    const float* bdt  = (const float*)d_in[8];
    const float* Alog = (const float*)d_in[9];
    const float* Dp   = (const float*)d_in[10];
    const float* Wo   = (const float*)d_in[11];
    const float* n2g  = (const float*)d_in[12];
    const float* n2b  = (const float*)d_in[13];
    const float* W1   = (const float*)d_in[14];
    const float* b1   = (const float*)d_in[15];
    const float* W2   = (const float*)d_in[16];
    const float* b2   = (const float*)d_in[17];
    float* out = (float*)d_out;
    float* ws  = (float*)d_ws;

    const size_t M1 = 1024 * 1024;
    // workspace layout (float units):
    ushort* xzb   = (ushort*)ws;                    // [0,4M)  bf16 [2048][4096]
    ushort* xcb   = (ushort*)(ws + 8*M1);           // [8M,10M) bf16 [2048][2048]
    ushort* dtb_b = (ushort*)(ws + 10*M1);          // [10M,12M) bf16 [2048][2048]
    float*  part  = ws + 14*M1;                     // [14M,17M) x_proj partials
    float*  hbuf  = ws + 14*M1;                     // reuse after reduce
    float*  dbc   = ws + 18*M1;                     // [18M,+196608) fp32 [2048][96]
    ushort* dtin_b= (ushort*)(ws + 18*M1 + 262144); // bf16 [2048][64]
    ushort* xnb   = (ushort*)(ws + 18*M1 + 524288); // bf16 [2048][1024]
    ushort* mb    = xnb;
    ushort* yb    = (ushort*)(ws + 20*M1);          // [20M,22M) bf16 [2048][2048]
    ushort* t1b   = yb;
    ushort* Wpb   = (ushort*)(ws + 22*M1);          // [22M,24M)
    float*  chunkA= ws + 22*M1;                     // reuse after in_proj (2M floats)
    ushort* Wob   = (ushort*)(ws + 24*M1);
    ushort* W1b   = (ushort*)(ws + 25*M1);
    ushort* W2b   = (ushort*)(ws + 26*M1);
    ushort* Wxb   = (ushort*)(ws + 27*M1);
    ushort* Wdtb  = (ushort*)(ws + 27*M1 + 131072);
    float*  chunkH = out;   // 2M fp32, overwritten by final GEMM (step 11)

    // 0+1. prep: weight converts + LN1 (one launch)
    prep_kernel<<<TOK + (2703360 + 255)/256, 256, 0, stream>>>(
        x, n1g, n1b, xnb, Wp, Wo, W1, W2, Wx, Wdt, Wpb, Wob, W1b, W2b, Wxb, Wdtb);

    // 2. in_proj (MFMA) -> bf16 xzb [row][4096]
    mfma_gemm<128,128,0,false,false,true><<<dim3(4096/128, 2048/128), 256, 0, stream>>>(
        xnb, Wpb, nullptr, nullptr, 0, xzb, 2*D_INNER, D_MODEL);
    // 3. conv + silu -> xcb bf16
    conv_silu_kernel<<<TOK*D_INNER/256, 256, 0, stream>>>(xzb, cw, cb, xcb);
    // 4. x_proj split-K MFMA + reduce -> dbc fp32, dtin_b bf16
    xproj_split_kernel<<<dim3(XKSPLIT, 2048/128), 256, 0, stream>>>(xcb, Wxb, part);
    xproj_reduce_kernel<<<(D_INNER*NBC + 255)/256, 256, 0, stream>>>(part, dbc, dtin_b);
    // 5. dt_proj (MFMA, softplus) -> dtb_b bf16, 512 blocks (64x128 tile)
    mfma_gemm<64,128,1,true,false,true><<<dim3(2048/128, 2048/64), 256, 0, stream>>>(
        dtin_b, Wdtb, bdt, nullptr, 0, dtb_b, D_INNER, DT_RANK);
    // 6. chunked selective scan (prefix fused into final), gate fused -> yb
    scan_chunk_kernel<<<BATCH*NCH*(D_INNER/64), 256, 0, stream>>>(dtb_b, dbc, xcb, Alog, chunkA, chunkH);
    scan_final_kernel<<<BATCH*NCH*(D_INNER/64), 256, 0, stream>>>(dtb_b, dbc, xcb, Alog,
                                                                  chunkA, chunkH, xzb, Dp, yb);
    // 8. out_proj (MFMA) + residual: hbuf = x + yb @ Wob^T, 512 blocks (64x64)
    mfma_gemm<64,64,0,false,true,false><<<dim3(1024/64, 2048/64), 256, 0, stream>>>(
        yb, Wob, nullptr, x, D_MODEL, hbuf, D_MODEL, D_INNER);
    // 9. LN2 -> bf16
    ln_bf16_kernel<<<TOK, 256, 0, stream>>>(hbuf, n2g, n2b, mb);
    // 10. mlp1 (MFMA, gelu) -> bf16, 512 blocks (64x128)
    mfma_gemm<64,128,2,true,false,true><<<dim3(2048/128, 2048/64), 256, 0, stream>>>(
        mb, W1b, b1, nullptr, 0, t1b, D_INNER, D_MODEL);
    // 11. mlp2 (MFMA) + bias + residual -> out, 512 blocks (64x64)
    mfma_gemm<64,64,0,true,true,false><<<dim3(1024/64, 2048/64), 256, 0, stream>>>(
        t1b, W2b, b2, hbuf, D_MODEL, out, D_MODEL, D_INNER);
}

// Round 15
// 220.633 us; speedup vs baseline: 1.0911x; 1.0911x over previous
//
#include <hip/hip_runtime.h>
#include <math.h>

#define D_MODEL 1024
#define D_INNER 2048
#define DT_RANK 64
#define D_STATE 16
#define NBC 96   // DT_RANK + 2*D_STATE
#define BATCH 2
#define SEQ 1024
#define TOK (BATCH*SEQ)  // 2048
#define CS 32            // scan chunk size
#define NCH 32           // chunks per sequence
#define XKSPLIT 16       // x_proj K-split

typedef __attribute__((ext_vector_type(8))) short short8;
typedef __attribute__((ext_vector_type(4))) float f32x4;
typedef __attribute__((ext_vector_type(4))) unsigned short us4;

// ---------------- device helpers ----------------
__device__ __forceinline__ float softplus_f(float x) {
    return (x > 20.0f) ? x : log1pf(__expf(x));
}
__device__ __forceinline__ float gelu_f(float x) {
    return 0.5f * x * (1.0f + erff(x * 0.70710678118654752f));
}
__device__ __forceinline__ float silu_f(float x) {
    return x / (1.0f + __expf(-x));
}
__device__ __forceinline__ ushort f2bf(float f) {   // fp32 -> bf16 RNE
    unsigned u = __float_as_uint(f);
    unsigned r = (u + 0x7fffu + ((u >> 16) & 1u)) >> 16;
    return (ushort)r;
}
__device__ __forceinline__ float bf2f(ushort u) {
    return __uint_as_float(((unsigned)u) << 16);
}

// ---------------- prep: LN1 (blocks 0..TOK-1) + weight converts (rest) ----------------
__global__ void prep_kernel(const float* __restrict__ x, const float* __restrict__ g,
                            const float* __restrict__ b, ushort* __restrict__ ln_out,
                            const float* __restrict__ Wp, const float* __restrict__ Wo,
                            const float* __restrict__ W1, const float* __restrict__ W2,
                            const float* __restrict__ Wx, const float* __restrict__ Wdt,
                            ushort* __restrict__ Wpb, ushort* __restrict__ Wob,
                            ushort* __restrict__ W1b, ushort* __restrict__ W2b,
                            ushort* __restrict__ Wxb, ushort* __restrict__ Wdtb) {
    int tid = threadIdx.x;
    if (blockIdx.x < TOK) {
        int row = blockIdx.x;
        const float* xr = x + (size_t)row * D_MODEL;
        ushort* outr = ln_out + (size_t)row * D_MODEL;
        float4 v = ((const float4*)xr)[tid];
        float s  = v.x + v.y + v.z + v.w;
        float sq = v.x*v.x + v.y*v.y + v.z*v.z + v.w*v.w;
        #pragma unroll
        for (int o = 32; o > 0; o >>= 1) {
            s  += __shfl_down(s,  o);
            sq += __shfl_down(sq, o);
        }
        __shared__ float ss[4], ssq[4];
        int wid = tid >> 6, lane = tid & 63;
        if (lane == 0) { ss[wid] = s; ssq[wid] = sq; }
        __syncthreads();
        if (tid == 0) {
            float a = 0.f, c = 0.f;
            for (int i = 0; i < 4; i++) { a += ss[i]; c += ssq[i]; }
            ss[0] = a; ssq[0] = c;
        }
        __syncthreads();
        float mean = ss[0] * (1.0f / D_MODEL);
        float var  = ssq[0] * (1.0f / D_MODEL) - mean * mean;
        float rstd = rsqrtf(var + 1e-5f);
        float4 gg = ((const float4*)g)[tid];
        float4 bb = ((const float4*)b)[tid];
        ushort4 o;
        o.x = f2bf((v.x - mean) * rstd * gg.x + bb.x);
        o.y = f2bf((v.y - mean) * rstd * gg.y + bb.y);
        o.z = f2bf((v.z - mean) * rstd * gg.z + bb.z);
        o.w = f2bf((v.w - mean) * rstd * gg.w + bb.w);
        ((ushort4*)outr)[tid] = o;
        return;
    }
    int i = (blockIdx.x - TOK) * 256 + tid;  // float4 index
    const float* src; ushort* dst; int off;
    if      (i < 1048576) { src = Wp;  dst = Wpb;  off = i; }
    else if (i < 1572864) { src = Wo;  dst = Wob;  off = i - 1048576; }
    else if (i < 2097152) { src = W1;  dst = W1b;  off = i - 1572864; }
    else if (i < 2621440) { src = W2;  dst = W2b;  off = i - 2097152; }
    else if (i < 2670592) { src = Wx;  dst = Wxb;  off = i - 2621440; }
    else if (i < 2703360) { src = Wdt; dst = Wdtb; off = i - 2670592; }
    else return;
    float4 v = ((const float4*)src)[off];
    ushort4 o;
    o.x = f2bf(v.x); o.y = f2bf(v.y); o.z = f2bf(v.z); o.w = f2bf(v.w);
    ((ushort4*)dst)[off] = o;
}

// ---------------- LayerNorm -> bf16 out (LN2) ----------------
__global__ void ln_bf16_kernel(const float* __restrict__ x, const float* __restrict__ g,
                               const float* __restrict__ b, ushort* __restrict__ out) {
    int row = blockIdx.x;
    const float* xr = x + (size_t)row * D_MODEL;
    ushort* outr = out + (size_t)row * D_MODEL;
    int tid = threadIdx.x;
    float4 v = ((const float4*)xr)[tid];
    float s  = v.x + v.y + v.z + v.w;
    float sq = v.x*v.x + v.y*v.y + v.z*v.z + v.w*v.w;
    #pragma unroll
    for (int o = 32; o > 0; o >>= 1) {
        s  += __shfl_down(s,  o);
        sq += __shfl_down(sq, o);
    }
    __shared__ float ss[4], ssq[4];
    int wid = tid >> 6, lane = tid & 63;
    if (lane == 0) { ss[wid] = s; ssq[wid] = sq; }
    __syncthreads();
    if (tid == 0) {
        float a = 0.f, c = 0.f;
        for (int i = 0; i < 4; i++) { a += ss[i]; c += ssq[i]; }
        ss[0] = a; ssq[0] = c;
    }
    __syncthreads();
    float mean = ss[0] * (1.0f / D_MODEL);
    float var  = ssq[0] * (1.0f / D_MODEL) - mean * mean;
    float rstd = rsqrtf(var + 1e-5f);
    float4 gg = ((const float4*)g)[tid];
    float4 bb = ((const float4*)b)[tid];
    ushort4 o;
    o.x = f2bf((v.x - mean) * rstd * gg.x + bb.x);
    o.y = f2bf((v.y - mean) * rstd * gg.y + bb.y);
    o.z = f2bf((v.z - mean) * rstd * gg.z + bb.z);
    o.w = f2bf((v.w - mean) * rstd * gg.w + bb.w);
    ((ushort4*)outr)[tid] = o;
}

// ---------------- bf16 MFMA GEMM, 2-phase prefetch double-buffer ----------------
// C = act(A @ W^T [+bias]) [+res]; ACT: 0=none, 1=softplus, 2=gelu
template<int BM, int BN, int ACT, bool BIAS, bool RES, bool OUTBF>
__global__ __launch_bounds__(256)
void mfma_gemm(const ushort* __restrict__ A, const ushort* __restrict__ W,
               const float* __restrict__ bias,
               const float* __restrict__ res, int ldr,
               void* __restrict__ Cout, int ldc, int K) {
    constexpr int WM = BM / 2, WN = BN / 2, FM = WM / 16, FN = WN / 16;
    __shared__ __align__(16) ushort As[2][BM * 32];
    __shared__ __align__(16) ushort Ws[2][BN * 32];
    const int tid  = threadIdx.x;
    const int lane = tid & 63, w = tid >> 6;
    const int wr = w >> 1, wc = w & 1;
    const int row0 = blockIdx.y * BM, col0 = blockIdx.x * BN;
    const int l16 = lane >> 4, l15 = lane & 15;
    const int srow = tid >> 2;
    const int scol = (tid & 3) * 8;
    const int nk = K / 32;

    f32x4 acc[FM][FN] = {};

    auto stage = [&](int kk, int buf) {
        const int k0 = kk * 32;
        #pragma unroll
        for (int s = 0; s < BM / 64; s++) {
            const ushort* g = A + (size_t)(row0 + s * 64 + srow) * K + k0 + scol;
            __builtin_amdgcn_global_load_lds(
                (const __attribute__((address_space(1))) void*)g,
                (__attribute__((address_space(3))) void*)((char*)&As[buf][0] + s * 4096 + w * 1024),
                16, 0, 0);
        }
        #pragma unroll
        for (int s = 0; s < BN / 64; s++) {
            const ushort* g = W + (size_t)(col0 + s * 64 + srow) * K + k0 + scol;
            __builtin_amdgcn_global_load_lds(
                (const __attribute__((address_space(1))) void*)g,
                (__attribute__((address_space(3))) void*)((char*)&Ws[buf][0] + s * 4096 + w * 1024),
                16, 0, 0);
        }
    };

    stage(0, 0);
    __syncthreads();

    for (int kk = 0; kk < nk; kk++) {
        const int cur = kk & 1;
        if (kk + 1 < nk) stage(kk + 1, cur ^ 1);

        short8 a[FM], b[FN];
        #pragma unroll
        for (int m = 0; m < FM; m++)
            a[m] = *(const short8*)(&As[cur][0] + (wr * WM + m * 16 + l15) * 32 + l16 * 8);
        #pragma unroll
        for (int n = 0; n < FN; n++)
            b[n] = *(const short8*)(&Ws[cur][0] + (wc * WN + n * 16 + l15) * 32 + l16 * 8);
        #pragma unroll
        for (int m = 0; m < FM; m++)
            #pragma unroll
            for (int n = 0; n < FN; n++)
                acc[m][n] = __builtin_amdgcn_mfma_f32_16x16x32_bf16(a[m], b[n], acc[m][n], 0, 0, 0);
        __syncthreads();
    }

    #pragma unroll
    for (int m = 0; m < FM; m++) {
        const int r0 = row0 + wr * WM + m * 16 + l16 * 4;
        #pragma unroll
        for (int n = 0; n < FN; n++) {
            const int c = col0 + wc * WN + n * 16 + l15;
            const float bv = BIAS ? bias[c] : 0.f;
            #pragma unroll
            for (int q = 0; q < 4; q++) {
                const int r = r0 + q;
                float v = acc[m][n][q] + bv;
                if (ACT == 1) v = softplus_f(v);
                else if (ACT == 2) v = gelu_f(v);
                if (RES) v += res[(size_t)r * ldr + c];
                if (OUTBF) ((ushort*)Cout)[(size_t)r * ldc + c] = f2bf(v);
                else       ((float*)Cout)[(size_t)r * ldc + c] = v;
            }
        }
    }
}

// ---------------- x_proj split-K MFMA (2-phase prefetch) ----------------
__global__ __launch_bounds__(256)
void xproj_split_kernel(const ushort* __restrict__ A,   // [2048][2048] bf16
                        const ushort* __restrict__ W,   // [96][2048] bf16
                        float* __restrict__ part) {     // [XKSPLIT][2048][96]
    __shared__ __align__(16) ushort As[2][128 * 64];
    __shared__ __align__(16) ushort Bs[2][96 * 64];
    const int tid = threadIdx.x;
    const int lane = tid & 63, w = tid >> 6;
    const int l16 = lane >> 4, l15 = lane & 15;
    const int kbase = blockIdx.x * (D_INNER / XKSPLIT);   // *128
    const int row0 = blockIdx.y * 128;
    const int srow = tid >> 3;        // 0..31
    const int scol = (tid & 7) * 8;   // 0..56

    f32x4 acc[2][6] = {};

    auto stage = [&](int k0, int buf) {
        #pragma unroll
        for (int s = 0; s < 4; s++) {
            const ushort* g = A + (size_t)(row0 + s * 32 + srow) * D_INNER + kbase + k0 + scol;
            __builtin_amdgcn_global_load_lds(
                (const __attribute__((address_space(1))) void*)g,
                (__attribute__((address_space(3))) void*)((char*)&As[buf][0] + s * 4096 + w * 1024),
                16, 0, 0);
        }
        #pragma unroll
        for (int s = 0; s < 3; s++) {
            const ushort* g = W + (size_t)(s * 32 + srow) * D_INNER + kbase + k0 + scol;
            __builtin_amdgcn_global_load_lds(
                (const __attribute__((address_space(1))) void*)g,
                (__attribute__((address_space(3))) void*)((char*)&Bs[buf][0] + s * 4096 + w * 1024),
                16, 0, 0);
        }
    };

    stage(0, 0);
    __syncthreads();

    const int nk = (D_INNER / XKSPLIT) / 64;   // 2
    for (int kk = 0; kk < nk; kk++) {
        const int cur = kk & 1;
        if (kk + 1 < nk) stage((kk + 1) * 64, cur ^ 1);
        #pragma unroll
        for (int ks = 0; ks < 2; ks++) {
            short8 a[2], b[6];
            #pragma unroll
            for (int m = 0; m < 2; m++)
                a[m] = *(const short8*)(&As[cur][0] + (w * 32 + m * 16 + l15) * 64 + ks * 32 + l16 * 8);
            #pragma unroll
            for (int n = 0; n < 6; n++)
                b[n] = *(const short8*)(&Bs[cur][0] + (n * 16 + l15) * 64 + ks * 32 + l16 * 8);
            #pragma unroll
            for (int m = 0; m < 2; m++)
                #pragma unroll
                for (int n = 0; n < 6; n++)
                    acc[m][n] = __builtin_amdgcn_mfma_f32_16x16x32_bf16(a[m], b[n], acc[m][n], 0, 0, 0);
        }
        __syncthreads();
    }

    float* p = part + (size_t)blockIdx.x * D_INNER * NBC;
    #pragma unroll
    for (int m = 0; m < 2; m++) {
        const int r0 = row0 + w * 32 + m * 16 + l16 * 4;
        #pragma unroll
        for (int n = 0; n < 6; n++) {
            const int c = n * 16 + l15;
            #pragma unroll
            for (int q = 0; q < 4; q++)
                p[(size_t)(r0 + q) * NBC + c] = acc[m][n][q];
        }
    }
}

// reduce 16 K-slices -> dbc fp32 [row][96]; emit bf16 of dt columns (c<64)
__global__ void xproj_reduce_kernel(const float* __restrict__ part,
                                    float* __restrict__ dbc, ushort* __restrict__ dtin_b) {
    int i = blockIdx.x * 256 + threadIdx.x;   // 2048*96
    if (i >= D_INNER * NBC) return;
    float s = 0.f;
    #pragma unroll
    for (int k = 0; k < XKSPLIT; k++) s += part[(size_t)k * D_INNER * NBC + i];
    dbc[i] = s;
    int r = i / NBC, c = i - r * NBC;
    if (c < DT_RANK) dtin_b[r * DT_RANK + c] = f2bf(s);
}

// ---------------- causal depthwise conv (k=4) + silu; channel-vectorized x4 ----------------
__global__ void conv_silu_kernel(const ushort* __restrict__ xzb, const float* __restrict__ cw,
                                 const float* __restrict__ cb, ushort* __restrict__ xcb) {
    int idx = blockIdx.x * 256 + threadIdx.x;      // TOK*D_INNER/4
    int c4 = (idx & (D_INNER / 4 - 1)) * 4;        // channel base (multiple of 4)
    int bt = idx >> 9;                             // token index
    int b  = bt >> 10;
    int t  = bt & (SEQ - 1);
    float4 bias4 = *(const float4*)(cb + c4);
    float acc[4] = {bias4.x, bias4.y, bias4.z, bias4.w};
    float4 w4[4];
    #pragma unroll
    for (int q = 0; q < 4; q++) w4[q] = *(const float4*)(cw + (c4 + q) * 4);
    #pragma unroll
    for (int j = 0; j < 4; j++) {
        int tt = t - 3 + j;
        if (tt >= 0) {
            us4 xv = *(const us4*)(xzb + ((size_t)(b * SEQ + tt)) * 4096 + c4);
            #pragma unroll
            for (int q = 0; q < 4; q++) acc[q] += w4[q][j] * bf2f(xv[q]);
        }
    }
    us4 o;
    #pragma unroll
    for (int q = 0; q < 4; q++) o[q] = f2bf(silu_f(acc[q]));
    *(us4*)(xcb + (size_t)bt * D_INNER + c4) = o;
}

// ---------------- chunked selective scan: LDS-staged; summaries in [b][c][d][n] ----------------
__global__ __launch_bounds__(256)
void scan_chunk_kernel(const ushort* __restrict__ dtb, const float* __restrict__ dbc,
                       const ushort* __restrict__ xcb, const float* __restrict__ A_log,
                       float* __restrict__ chunkA, float* __restrict__ chunkH) {
    __shared__ ushort dtS[64][36];
    __shared__ ushort xS[64][36];
    __shared__ float  BS[16][36];
    const int bid = blockIdx.x;
    const int dg = bid & 31, cc = (bid >> 5) & 31, b = bid >> 10;
    const int d0 = dg * 64;
    const int tid = threadIdx.x, lane = tid & 63, wv = tid >> 6;
    const int rbase = b * SEQ + cc * CS;

    #pragma unroll
    for (int k = 0; k < 8; k++) {
        int tt = k * 4 + wv;
        size_t row = (size_t)(rbase + tt);
        dtS[lane][tt] = dtb[row * D_INNER + d0 + lane];
        xS[lane][tt]  = xcb[row * D_INNER + d0 + lane];
    }
    #pragma unroll
    for (int k = 0; k < 2; k++) {
        int ii = k * 256 + tid;          // 0..511
        int val = ii & 15, tt = ii >> 4;
        BS[val][tt] = dbc[(size_t)(rbase + tt) * NBC + DT_RANK + val];
    }
    __syncthreads();

    const int d_local = tid >> 2, ng = tid & 3, nb = ng * 4;
    const int d = d0 + d_local;
    float Arow[4];
    #pragma unroll
    for (int j = 0; j < 4; j++) Arow[j] = -__expf(A_log[d * D_STATE + nb + j]);
    float h[4] = {};
    float ap[4] = {1.f, 1.f, 1.f, 1.f};
    #pragma unroll
    for (int it = 0; it < 8; ++it) {
        us4 dtu = *(const us4*)&dtS[d_local][it * 4];
        us4 xu  = *(const us4*)&xS[d_local][it * 4];
        f32x4 Bv[4];
        #pragma unroll
        for (int j = 0; j < 4; j++) Bv[j] = *(const f32x4*)&BS[nb + j][it * 4];
        #pragma unroll
        for (int q = 0; q < 4; ++q) {
            float dtv = bf2f(dtu[q]);
            float dtx = dtv * bf2f(xu[q]);
            #pragma unroll
            for (int j = 0; j < 4; j++) {
                float dA = __expf(dtv * Arow[j]);
                ap[j] *= dA;
                h[j] = dA * h[j] + dtx * Bv[j][q];
            }
        }
    }
    // summary layout: ((b*NCH+c)*D_INNER + d)*D_STATE + n  -> f32x4 store
    size_t obase = ((size_t)((b * NCH + cc) * D_INNER) + d) * D_STATE + nb;
    f32x4 av, hv;
    #pragma unroll
    for (int j = 0; j < 4; j++) { av[j] = ap[j]; hv[j] = h[j]; }
    *(f32x4*)&chunkA[obase] = av;
    *(f32x4*)&chunkH[obase] = hv;
}

// pass2: in-register prefix over preceding chunks, seeded scan + fused gate -> yb bf16
__global__ __launch_bounds__(256)
void scan_final_kernel(const ushort* __restrict__ dtb, const float* __restrict__ dbc,
                       const ushort* __restrict__ xcb, const float* __restrict__ A_log,
                       const float* __restrict__ chunkA, const float* __restrict__ chunkH,
                       const ushort* __restrict__ xzb,
                       const float* __restrict__ Dp, ushort* __restrict__ yb) {
    __shared__ ushort dtS[64][36];
    __shared__ ushort xS[64][36];
    __shared__ ushort zS[64][36];
    __shared__ float  BS[16][36];
    __shared__ float  CSld[16][36];
    __shared__ ushort ySt[64][36];
    const int bid = blockIdx.x;
    const int dg = bid & 31, cc = (bid >> 5) & 31, b = bid >> 10;
    const int d0 = dg * 64;
    const int tid = threadIdx.x, lane = tid & 63, wv = tid >> 6;
    const int rbase = b * SEQ + cc * CS;

    #pragma unroll
    for (int k = 0; k < 8; k++) {
        int tt = k * 4 + wv;
        size_t row = (size_t)(rbase + tt);
        dtS[lane][tt] = dtb[row * D_INNER + d0 + lane];
        xS[lane][tt]  = xcb[row * D_INNER + d0 + lane];
        zS[lane][tt]  = xzb[row * 4096 + 2048 + d0 + lane];
    }
    #pragma unroll
    for (int k = 0; k < 4; k++) {
        int ii = k * 256 + tid;          // 0..1023
        int val = ii & 31, tt = ii >> 5;
        float v = dbc[(size_t)(rbase + tt) * NBC + DT_RANK + val];
        if (val < 16) BS[val][tt] = v;
        else          CSld[val - 16][tt] = v;
    }

    const int d_local = tid >> 2, ng = tid & 3, nb = ng * 4;
    const int d = d0 + d_local;

    // in-register prefix over chunk summaries: hIn for this chunk
    f32x4 hv = {0.f, 0.f, 0.f, 0.f};
    #pragma unroll 4
    for (int c = 0; c < cc; ++c) {
        size_t off = ((size_t)((b * NCH + c) * D_INNER) + d) * D_STATE + nb;
        f32x4 a  = *(const f32x4*)&chunkA[off];
        f32x4 hl = *(const f32x4*)&chunkH[off];
        hv = a * hv + hl;
    }
    float Arow[4];
    #pragma unroll
    for (int j = 0; j < 4; j++) Arow[j] = -__expf(A_log[d * D_STATE + nb + j]);
    float h[4];
    #pragma unroll
    for (int j = 0; j < 4; j++) h[j] = hv[j];
    const float Dpv = Dp[d];
    __syncthreads();

    #pragma unroll
    for (int it = 0; it < 8; ++it) {
        us4 dtu = *(const us4*)&dtS[d_local][it * 4];
        us4 xu  = *(const us4*)&xS[d_local][it * 4];
        f32x4 Bv[4], Cv[4];
        #pragma unroll
        for (int j = 0; j < 4; j++) {
            Bv[j] = *(const f32x4*)&BS[nb + j][it * 4];
            Cv[j] = *(const f32x4*)&CSld[nb + j][it * 4];
        }
        float yv4[4];
        #pragma unroll
        for (int q = 0; q < 4; ++q) {
            float dtv = bf2f(dtu[q]);
            float dtx = dtv * bf2f(xu[q]);
            float yv = 0.f;
            #pragma unroll
            for (int j = 0; j < 4; j++) {
                float dA = __expf(dtv * Arow[j]);
                h[j] = dA * h[j] + dtx * Bv[j][q];
                yv += h[j] * Cv[j][q];
            }
            yv4[q] = yv;
        }
        #pragma unroll
        for (int q = 0; q < 4; ++q) {
            yv4[q] += __shfl_xor(yv4[q], 1);
            yv4[q] += __shfl_xor(yv4[q], 2);
        }
        if (ng == 0) {
            us4 zu = *(const us4*)&zS[d_local][it * 4];
            us4 xo = *(const us4*)&xS[d_local][it * 4];
            us4 o;
            #pragma unroll
            for (int q = 0; q < 4; ++q) {
                float z = bf2f(zu[q]);
                o[q] = f2bf((yv4[q] + bf2f(xo[q]) * Dpv) * silu_f(z));
            }
            *(us4*)&ySt[d_local][it * 4] = o;
        }
    }
    __syncthreads();
    #pragma unroll
    for (int k = 0; k < 8; k++) {
        int tt = k * 4 + wv;
        yb[(size_t)(rbase + tt) * D_INNER + d0 + lane] = ySt[lane][tt];
    }
}

// ---------------- launch ----------------
extern "C" void kernel_launch(void* const* d_in, const int* in_sizes, int n_in,
                              void* d_out, int out_size, void* d_ws, size_t ws_size,
                              hipStream_t stream) {
    const float* x    = (const float*)d_in[0];
    const float* n1g  = (const float*)d_in[1];
    const float* n1b  = (const float*)d_in[2];
    const float* Wp   = (const float*)d_in[3];
    const float* cw   = (const float*)d_in[4];
    const float* cb   = (const float*)d_in[5];
    const float* Wx   = (const float*)d_in[6];
    const float* Wdt  = (const float*)d_in[7];
    const float* bdt  = (const float*)d_in[8];
    const float* Alog = (const float*)d_in[9];
    const float* Dp   = (const float*)d_in[10];
    const float* Wo   = (const float*)d_in[11];
    const float* n2g  = (const float*)d_in[12];
    const float* n2b  = (const float*)d_in[13];
    const float* W1   = (const float*)d_in[14];
    const float* b1   = (const float*)d_in[15];
    const float* W2   = (const float*)d_in[16];
    const float* b2   = (const float*)d_in[17];
    float* out = (float*)d_out;
    float* ws  = (float*)d_ws;

    const size_t M1 = 1024 * 1024;
    // workspace layout (float units):
    ushort* xzb   = (ushort*)ws;                    // [0,4M)  bf16 [2048][4096]
    ushort* xcb   = (ushort*)(ws + 8*M1);           // [8M,10M) bf16 [2048][2048]
    ushort* dtb_b = (ushort*)(ws + 10*M1);          // [10M,12M) bf16 [2048][2048]
    float*  part  = ws + 14*M1;                     // [14M,17M) x_proj partials
    float*  hbuf  = ws + 14*M1;                     // reuse after reduce
    float*  dbc   = ws + 18*M1;                     // [18M,+196608) fp32 [2048][96]
    ushort* dtin_b= (ushort*)(ws + 18*M1 + 262144); // bf16 [2048][64]
    ushort* xnb   = (ushort*)(ws + 18*M1 + 524288); // bf16 [2048][1024]
    ushort* mb    = xnb;
    ushort* yb    = (ushort*)(ws + 20*M1);          // [20M,22M) bf16 [2048][2048]
    ushort* t1b   = yb;
    ushort* Wpb   = (ushort*)(ws + 22*M1);          // [22M,24M)
    float*  chunkA= ws + 22*M1;                     // reuse after in_proj (2M floats)
    ushort* Wob   = (ushort*)(ws + 24*M1);
    ushort* W1b   = (ushort*)(ws + 25*M1);
    ushort* W2b   = (ushort*)(ws + 26*M1);
    ushort* Wxb   = (ushort*)(ws + 27*M1);
    ushort* Wdtb  = (ushort*)(ws + 27*M1 + 131072);
    float*  chunkH = out;   // 2M fp32, overwritten by final GEMM (step 11)

    // 0+1. prep: weight converts + LN1 (one launch)
    prep_kernel<<<TOK + (2703360 + 255)/256, 256, 0, stream>>>(
        x, n1g, n1b, xnb, Wp, Wo, W1, W2, Wx, Wdt, Wpb, Wob, W1b, W2b, Wxb, Wdtb);

    // 2. in_proj (MFMA) -> bf16 xzb [row][4096]
    mfma_gemm<128,128,0,false,false,true><<<dim3(4096/128, 2048/128), 256, 0, stream>>>(
        xnb, Wpb, nullptr, nullptr, 0, xzb, 2*D_INNER, D_MODEL);
    // 3. conv + silu -> xcb bf16 (channel-vectorized x4)
    conv_silu_kernel<<<TOK*D_INNER/4/256, 256, 0, stream>>>(xzb, cw, cb, xcb);
    // 4. x_proj split-K MFMA + reduce -> dbc fp32, dtin_b bf16
    xproj_split_kernel<<<dim3(XKSPLIT, 2048/128), 256, 0, stream>>>(xcb, Wxb, part);
    xproj_reduce_kernel<<<(D_INNER*NBC + 255)/256, 256, 0, stream>>>(part, dbc, dtin_b);
    // 5. dt_proj (MFMA, softplus) -> dtb_b bf16, 512 blocks (64x128 tile)
    mfma_gemm<64,128,1,true,false,true><<<dim3(2048/128, 2048/64), 256, 0, stream>>>(
        dtin_b, Wdtb, bdt, nullptr, 0, dtb_b, D_INNER, DT_RANK);
    // 6. chunked selective scan (prefix fused into final), gate fused -> yb
    scan_chunk_kernel<<<BATCH*NCH*(D_INNER/64), 256, 0, stream>>>(dtb_b, dbc, xcb, Alog, chunkA, chunkH);
    scan_final_kernel<<<BATCH*NCH*(D_INNER/64), 256, 0, stream>>>(dtb_b, dbc, xcb, Alog,
                                                                  chunkA, chunkH, xzb, Dp, yb);
    // 8. out_proj (MFMA) + residual: hbuf = x + yb @ Wob^T, 512 blocks (64x64)
    mfma_gemm<64,64,0,false,true,false><<<dim3(1024/64, 2048/64), 256, 0, stream>>>(
        yb, Wob, nullptr, x, D_MODEL, hbuf, D_MODEL, D_INNER);
    // 9. LN2 -> bf16
    ln_bf16_kernel<<<TOK, 256, 0, stream>>>(hbuf, n2g, n2b, mb);
    // 10. mlp1 (MFMA, gelu) -> bf16, 512 blocks (64x128)
    mfma_gemm<64,128,2,true,false,true><<<dim3(2048/128, 2048/64), 256, 0, stream>>>(
        mb, W1b, b1, nullptr, 0, t1b, D_INNER, D_MODEL);
    // 11. mlp2 (MFMA) + bias + residual -> out, 512 blocks (64x64)
    mfma_gemm<64,64,0,true,true,false><<<dim3(1024/64, 2048/64), 256, 0, stream>>>(
        t1b, W2b, b2, hbuf, D_MODEL, out, D_MODEL, D_INNER);
}